// Round 14
// baseline (823.054 us; speedup 1.0000x reference)
//
#include <hip/hip_runtime.h>

#define EPSV 1e-5f

typedef unsigned short u16;
typedef __attribute__((ext_vector_type(8))) _Float16 half8;
typedef __attribute__((ext_vector_type(4))) float floatx4;

__device__ __forceinline__ float h2f(u16 h) {
    return (float)__builtin_bit_cast(_Float16, h);
}
__device__ __forceinline__ u16 f2h(float f) {
    _Float16 h = (_Float16)f;
    return __builtin_bit_cast(u16, h);
}

// ---------------------------------------------------------------------------
// NT fp16 MFMA GEMM: D[i][j] = sum_k A[i][k] * B[j][k]
// A: [I][ldA] fp16 (K contiguous), B: [J][ldB] fp16 (K contiguous)
// Tile 128x128, BK=32, 256 threads (4 waves, 2x2 quadrants, 16 MFMAs each).
// SHALLOW 2-buffer pipeline -- measured-best core after 5 structural
// experiments (deep vmcnt R6/R7 null, 128x64 tiles R8 worse, split-K R11
// null net, 256^2 phase-split R12 worse). Cross-dispatch rates show this
// latency-bound loop runs ~2x faster on L3-hot inputs (upd/logits/u >520 TF)
// than HBM-cold ones (f 261 TF) -- hence the launch-side chunking of
// transpose+f below to keep featT L3-resident.
// MODE: 0 = plain, 1 = BN+ReLU per col j, 2 = BN+ReLU per row i,
//       3 = add fp16 tensor `addf`
// ---------------------------------------------------------------------------
template <int MODE, typename OUTT>
__global__ __launch_bounds__(256)
void gemm_nt(const u16* __restrict__ A, const u16* __restrict__ B,
             OUTT* __restrict__ C_,
             const float* __restrict__ inv_, const float* __restrict__ beta_,
             const u16* __restrict__ addf,
             int K, int ldA, int ldB, int ldC,
             long strideA, long strideB, long strideC)
{
    __shared__ u16 As[2][128 * 32];
    __shared__ u16 Bs[2][128 * 32];

    const int tid = threadIdx.x;
    const int w = tid >> 6;        // wave 0..3
    const int l = tid & 63;        // lane

    // XCD-chunked bijective swizzle: all our grids have nwg % 8 == 0.
    int bx = blockIdx.x, by = blockIdx.y, bz = blockIdx.z;
    {
        const int gx = gridDim.x, gy = gridDim.y;
        const int nwg = gx * gy * (int)gridDim.z;
        if ((nwg & 7) == 0) {
            const int lin = bx + gx * (by + gy * bz);
            const int swz = (lin & 7) * (nwg >> 3) + (lin >> 3);
            bx = swz % gx;
            const int t = swz / gx;
            by = t % gy;
            bz = t / gy;
        }
    }
    const int j0 = bx * 128;
    const int i0 = by * 128;

    const u16* Ab = A + (long)bz * strideA;
    const u16* Bb = B + (long)bz * strideB;

    // staging: per issue, wave w covers 16 rows (lane/4), granule (lane&3)*8
    const int srow = w * 16 + (l >> 2);   // 0..63 (+64 for second issue)
    const int skel = (l & 3) * 8;         // k element offset

    // compute mapping: wave quadrant
    const int i_base = (w >> 1) * 64;
    const int j_base = (w & 1) * 64;
    const int lm = l & 15;
    const int kq = l >> 4;                // 0..3

    floatx4 acc[4][4];
    #pragma unroll
    for (int a = 0; a < 4; ++a)
        #pragma unroll
        for (int b = 0; b < 4; ++b) acc[a][b] = (floatx4)(0.0f);

    auto stage = [&](int buf, int k0) {
        const u16* ga0 = Ab + (long)(i0 + srow) * ldA + k0 + skel;
        const u16* ga1 = Ab + (long)(i0 + 64 + srow) * ldA + k0 + skel;
        const u16* gb0 = Bb + (long)(j0 + srow) * ldB + k0 + skel;
        const u16* gb1 = Bb + (long)(j0 + 64 + srow) * ldB + k0 + skel;
        char* la0 = (char*)&As[buf][0] + w * 1024;
        char* la1 = (char*)&As[buf][0] + 4096 + w * 1024;
        char* lb0 = (char*)&Bs[buf][0] + w * 1024;
        char* lb1 = (char*)&Bs[buf][0] + 4096 + w * 1024;
        __builtin_amdgcn_global_load_lds(
            (const __attribute__((address_space(1))) unsigned int*)(const void*)ga0,
            (__attribute__((address_space(3))) unsigned int*)(void*)la0, 16, 0, 0);
        __builtin_amdgcn_global_load_lds(
            (const __attribute__((address_space(1))) unsigned int*)(const void*)ga1,
            (__attribute__((address_space(3))) unsigned int*)(void*)la1, 16, 0, 0);
        __builtin_amdgcn_global_load_lds(
            (const __attribute__((address_space(1))) unsigned int*)(const void*)gb0,
            (__attribute__((address_space(3))) unsigned int*)(void*)lb0, 16, 0, 0);
        __builtin_amdgcn_global_load_lds(
            (const __attribute__((address_space(1))) unsigned int*)(const void*)gb1,
            (__attribute__((address_space(3))) unsigned int*)(void*)lb1, 16, 0, 0);
    };

    const int nt = K >> 5;            // K-tiles of 32
    stage(0, 0);
    __syncthreads();
    int cur = 0;
    for (int t = 0; t < nt; ++t) {
        if (t + 1 < nt) stage(cur ^ 1, (t + 1) << 5);

        const u16* Ac = &As[cur][0];
        const u16* Bc = &Bs[cur][0];
        half8 af[4], bf[4];
        #pragma unroll
        for (int tt = 0; tt < 4; ++tt) {
            af[tt] = *(const half8*)&Ac[(i_base + tt * 16 + lm) * 32 + kq * 8];
            bf[tt] = *(const half8*)&Bc[(j_base + tt * 16 + lm) * 32 + kq * 8];
        }
        #pragma unroll
        for (int ti = 0; ti < 4; ++ti)
            #pragma unroll
            for (int tj = 0; tj < 4; ++tj)
                acc[ti][tj] = __builtin_amdgcn_mfma_f32_16x16x32_f16(
                    af[ti], bf[tj], acc[ti][tj], 0, 0, 0);
        __syncthreads();
        cur ^= 1;
    }

    OUTT* Cb = C_ + (long)bz * strideC;
    const u16* addb = (MODE == 3) ? addf + (long)bz * strideC : nullptr;
    #pragma unroll
    for (int ti = 0; ti < 4; ++ti) {
        #pragma unroll
        for (int tj = 0; tj < 4; ++tj) {
            const int jj = j0 + j_base + tj * 16 + lm;
            float cinv = 0.f, cbeta = 0.f;
            if (MODE == 1) { cinv = inv_[jj]; cbeta = beta_[jj]; }
            #pragma unroll
            for (int r = 0; r < 4; ++r) {
                const int ii = i0 + i_base + ti * 16 + kq * 4 + r;
                float val = acc[ti][tj][r];
                if (MODE == 1) val = fmaxf(val * cinv + cbeta, 0.0f);
                if (MODE == 2) {
                    float iv = inv_[ii], bt = beta_[ii];
                    val = fmaxf(val * iv + bt, 0.0f);
                }
                if (MODE == 3) val += h2f(addb[(long)ii * ldC + jj]);
                if (sizeof(OUTT) == 4) {
                    ((float*)Cb)[(long)ii * ldC + jj] = val;
                } else {
                    ((u16*)Cb)[(long)ii * ldC + jj] = f2h(val);
                }
            }
        }
    }
}

// ---------------------------------------------------------------------------
// weight fp32 -> fp16 + precompute BN inv/beta
// ---------------------------------------------------------------------------
__global__ __launch_bounds__(256)
void conv_weight(const float* __restrict__ W, const float* __restrict__ g,
                 const float* __restrict__ b, const float* __restrict__ m,
                 const float* __restrict__ v,
                 u16* __restrict__ Wb, float* __restrict__ inv_,
                 float* __restrict__ beta_, int cout, long n)
{
    for (long idx = (long)blockIdx.x * 256 + threadIdx.x; idx < n;
         idx += (long)gridDim.x * 256)
        Wb[idx] = f2h(W[idx]);
    int c = blockIdx.x * 256 + threadIdx.x;
    if (c < cout) {
        float iv = g[c] * rsqrtf(v[c] + EPSV);
        inv_[c] = iv;
        beta_[c] = b[c] - m[c] * iv;
    }
}

// ---------------------------------------------------------------------------
// feature [C][N] fp32 -> featT [N][C] fp16 (32x32 tiled transpose), per batch z
// ---------------------------------------------------------------------------
__global__ __launch_bounds__(256)
void transpose_conv(const float* __restrict__ in, u16* __restrict__ out,
                    int C, int N)
{
    __shared__ float t[32][33];
    const int n0 = blockIdx.x * 32, c0 = blockIdx.y * 32;
    const float* inb = in + (long)blockIdx.z * C * N;
    u16* outb = out + (long)blockIdx.z * C * N;
    const int tx = threadIdx.x & 31, ty = threadIdx.x >> 5;  // 32 x 8
    #pragma unroll
    for (int rr = 0; rr < 32; rr += 8)
        t[ty + rr][tx] = inb[(long)(c0 + ty + rr) * N + n0 + tx];
    __syncthreads();
    #pragma unroll
    for (int rr = 0; rr < 32; rr += 8)
        outb[(long)(n0 + ty + rr) * C + c0 + tx] = f2h(t[tx][ty + rr]);
}

// ---------------------------------------------------------------------------
// Row softmax for ONE batch: reads S fp16 [4096][4096] (L3-hot from the
// preceding logits GEMM), writes compact P fp16.
// ---------------------------------------------------------------------------
__global__ __launch_bounds__(256)
void softmax_f16(const u16* __restrict__ S, u16* __restrict__ P)
{
    __shared__ float buf[4096];
    __shared__ float red[256];
    const u16* p = S + (long)blockIdx.x * 4096;
    u16* o = P + (long)blockIdx.x * 4096;
    const int tid = threadIdx.x;

    float lmax = -3.4e38f;
    for (int i = tid; i < 4096; i += 256) {
        float x = h2f(p[i]);
        buf[i] = x;
        lmax = fmaxf(lmax, x);
    }
    red[tid] = lmax;
    __syncthreads();
    for (int s = 128; s > 0; s >>= 1) {
        if (tid < s) red[tid] = fmaxf(red[tid], red[tid + s]);
        __syncthreads();
    }
    const float mx = red[0];
    __syncthreads();

    float lsum = 0.0f;
    for (int i = tid; i < 4096; i += 256) {
        float e = __expf(buf[i] - mx);
        buf[i] = e;
        lsum += e;
    }
    red[tid] = lsum;
    __syncthreads();
    for (int s = 128; s > 0; s >>= 1) {
        if (tid < s) red[tid] += red[tid + s];
        __syncthreads();
    }
    const float invs = 1.0f / red[0];
    __syncthreads();

    for (int i = tid; i < 4096; i += 256) o[i] = f2h(buf[i] * invs);
}

// ---------------------------------------------------------------------------
extern "C" void kernel_launch(void* const* d_in, const int* in_sizes, int n_in,
                              void* d_out, int out_size, void* d_ws, size_t ws_size,
                              hipStream_t stream)
{
    (void)in_sizes; (void)n_in; (void)out_size; (void)ws_size;
    constexpr int B = 4, C = 2048, R = 512, N = 4096;
    constexpr long NR = (long)N * R;     // 2,097,152
    constexpr long NC = (long)N * C;     // 8,388,608
    constexpr long NN = (long)N * N;     // 16,777,216
    constexpr long NQK = (long)N * 1024;

    const float* feature = (const float*)d_in[0];
    const float* W_[5]  = {(const float*)d_in[1],  (const float*)d_in[6],
                           (const float*)d_in[11], (const float*)d_in[16],
                           (const float*)d_in[21]};
    const float* G_[5]  = {(const float*)d_in[2],  (const float*)d_in[7],
                           (const float*)d_in[12], (const float*)d_in[17],
                           (const float*)d_in[22]};
    const float* Bb_[5] = {(const float*)d_in[3],  (const float*)d_in[8],
                           (const float*)d_in[13], (const float*)d_in[18],
                           (const float*)d_in[23]};
    const float* M_[5]  = {(const float*)d_in[4],  (const float*)d_in[9],
                           (const float*)d_in[14], (const float*)d_in[19],
                           (const float*)d_in[24]};
    const float* V_[5]  = {(const float*)d_in[5],  (const float*)d_in[10],
                           (const float*)d_in[15], (const float*)d_in[20],
                           (const float*)d_in[25]};

    // ---- workspace layout (bytes), ws = 512 MiB ----
    char* base = (char*)d_ws;
    size_t off = 0;
    // region0 (134 MB): S fp16 [B][N][N] during logits/softmax.
    // featT fp16 [B][N][C] (67 MB) aliases its head -- dead before logits.
    u16* S     = (u16*)base;
    u16* featT = (u16*)base;
    off += (size_t)B * NN * 2;                         // 134,217,728
    u16* fT  = (u16*)(base + off);                     off += (size_t)B * NR * 2;
    u16* qkT = (u16*)(base + off);                     off += (size_t)B * NQK * 2;
    u16* vC  = (u16*)(base + off);                     off += (size_t)B * NR * 2;
    u16* gT  = (u16*)(base + off);                     off += (size_t)B * NR * 2;
    u16* Pc  = (u16*)(base + off);                     off += (size_t)B * NN * 2;
    // weights (fp16)
    u16* Wb_r  = (u16*)(base + off);  off += (size_t)R * C * 2;       // 2 MB
    u16* WbQK  = (u16*)(base + off);  off += (size_t)1024 * R * 2;    // 1 MB
    u16* Wb_v  = (u16*)(base + off);  off += (size_t)R * R * 2;       // 0.5 MB
    u16* Wb_u  = (u16*)(base + off);  off += (size_t)C * R * 2;       // 2 MB
    off = (off + 255) & ~(size_t)255;
    // BN params
    float* inv_r  = (float*)(base + off);  off += 8192;
    float* beta_r = (float*)(base + off);  off += 8192;
    float* invQK  = (float*)(base + off);  off += 8192;   // [1024]
    float* betaQK = (float*)(base + off);  off += 8192;   // [1024]
    float* inv_v  = (float*)(base + off);  off += 8192;
    float* beta_v = (float*)(base + off);  off += 8192;
    float* inv_u  = (float*)(base + off);  off += 8192;   // [2048]
    float* beta_u = (float*)(base + off);  off += 8192;

    float* out = (float*)d_out;
    const dim3 blk(256);

    // ---- weight conversion + BN param precompute ----
    conv_weight<<<512, blk, 0, stream>>>(W_[0], G_[0], Bb_[0], M_[0], V_[0],
                                         Wb_r, inv_r, beta_r, R, (long)R * C);
    conv_weight<<<512, blk, 0, stream>>>(W_[1], G_[1], Bb_[1], M_[1], V_[1],
                                         WbQK, invQK, betaQK, R, (long)R * R);
    conv_weight<<<512, blk, 0, stream>>>(W_[2], G_[2], Bb_[2], M_[2], V_[2],
                                         WbQK + (size_t)R * R, invQK + R, betaQK + R,
                                         R, (long)R * R);
    conv_weight<<<512, blk, 0, stream>>>(W_[3], G_[3], Bb_[3], M_[3], V_[3],
                                         Wb_v, inv_v, beta_v, R, (long)R * R);
    conv_weight<<<512, blk, 0, stream>>>(W_[4], G_[4], Bb_[4], M_[4], V_[4],
                                         Wb_u, inv_u, beta_u, C, (long)C * R);

    // ---- transpose + f, CHUNKED x2 (2 batches per chunk):
    // per chunk: transpose streams 134 MB fp32 read + 33.5 MB featT write
    // (167 MB < 256 MB L3 -> featT-half stays L3-resident), then f-half
    // reads it L3-hot. f-half grid (4,64) = 256 wgs = full machine. ----
    for (int h = 0; h < 2; ++h) {
        const long boff = (long)h * 2;    // first batch of chunk
        transpose_conv<<<dim3(N / 32, C / 32, 2), blk, 0, stream>>>(
            feature + boff * NC, featT + boff * NC, C, N);
        gemm_nt<1, u16><<<dim3(R / 128, (2 * N) / 128, 1), blk, 0, stream>>>(
            featT + boff * NC, Wb_r, fT + boff * NR, inv_r, beta_r, nullptr,
            C, C, C, R, 0, 0, 0);
    }

    // ---- q,k merged: qkT [B][N][1024], grid 1024 ----
    gemm_nt<1, u16><<<dim3(1024 / 128, N / 128, B), blk, 0, stream>>>(
        fT, WbQK, qkT, invQK, betaQK, nullptr,
        R, R, R, 1024, NR, 0, NQK);

    // ---- v = CBR(f), channel-major: vC [B][R][N], grid 512 ----
    gemm_nt<2, u16><<<dim3(N / 128, R / 128, B), blk, 0, stream>>>(
        Wb_v, fT, vC, inv_v, beta_v, nullptr,
        R, R, R, N, 0, NR, NR);

    // ---- logits (fp16 S) + softmax PER BATCH: S[b] = 33.5 MB stays
    // L3-hot for the softmax that consumes it. ----
    for (int b = 0; b < B; ++b) {
        gemm_nt<0, u16><<<dim3(N / 128, N / 128, 1), blk, 0, stream>>>(
            qkT + (long)b * NQK, qkT + (long)b * NQK + 512, S + (long)b * NN,
            nullptr, nullptr, nullptr,
            R, 1024, 1024, N, 0, 0, 0);
        softmax_f16<<<dim3(N), blk, 0, stream>>>(S + (long)b * NN,
                                                 Pc + (long)b * NN);
    }

    // ---- upd: gT[b][n][c] = fT + sum_m P[n][m]*vC[c][m], grid 512 ----
    gemm_nt<3, u16><<<dim3(R / 128, N / 128, B), blk, 0, stream>>>(
        Pc, vC, gT, nullptr, nullptr, fT,
        N, N, N, R, NN, NR, NR);

    // ---- out = CBR(f + upd, u): grid 2048 ----
    gemm_nt<2, float><<<dim3(N / 128, C / 128, B), blk, 0, stream>>>(
        Wb_u, gT, out, inv_u, beta_u, nullptr,
        R, R, R, N, 0, NR, NC);
}

// Round 15
// 726.818 us; speedup vs baseline: 1.1324x; 1.1324x over previous
//
#include <hip/hip_runtime.h>

#define EPSV 1e-5f

typedef unsigned short u16;
typedef __attribute__((ext_vector_type(8))) _Float16 half8;
typedef __attribute__((ext_vector_type(4))) float floatx4;

__device__ __forceinline__ float h2f(u16 h) {
    return (float)__builtin_bit_cast(_Float16, h);
}
__device__ __forceinline__ u16 f2h(float f) {
    _Float16 h = (_Float16)f;
    return __builtin_bit_cast(u16, h);
}

// ---------------------------------------------------------------------------
// NT fp16 MFMA GEMM: D[i][j] = sum_k A[i][k] * B[j][k]
// A: [I][ldA] fp16 (K contiguous), B: [J][ldB] fp16 (K contiguous)
// Tile 128x128, BK=32, 256 threads (4 waves, 2x2 quadrants, 16 MFMAs each).
// SHALLOW 2-buffer pipeline -- measured-best core after 5 structural
// experiments (deep vmcnt R6/R7 null, 128x64 tiles R8 worse, split-K R11
// null net, 256^2 phase-split R12 worse, chunked-launch R14 worse via
// occupancy loss). Latency-bound: ~260 TF on HBM-cold input, ~520+ TF on
// L3-hot input -- so the launch side manages L3 residency (nt-loads on
// streams, single-S reuse) instead of touching this core.
// MODE: 0 = plain, 1 = BN+ReLU per col j, 2 = BN+ReLU per row i,
//       3 = add fp16 tensor `addf`
// ---------------------------------------------------------------------------
template <int MODE, typename OUTT>
__global__ __launch_bounds__(256)
void gemm_nt(const u16* __restrict__ A, const u16* __restrict__ B,
             OUTT* __restrict__ C_,
             const float* __restrict__ inv_, const float* __restrict__ beta_,
             const u16* __restrict__ addf,
             int K, int ldA, int ldB, int ldC,
             long strideA, long strideB, long strideC)
{
    __shared__ u16 As[2][128 * 32];
    __shared__ u16 Bs[2][128 * 32];

    const int tid = threadIdx.x;
    const int w = tid >> 6;        // wave 0..3
    const int l = tid & 63;        // lane

    // XCD-chunked bijective swizzle: all our grids have nwg % 8 == 0.
    int bx = blockIdx.x, by = blockIdx.y, bz = blockIdx.z;
    {
        const int gx = gridDim.x, gy = gridDim.y;
        const int nwg = gx * gy * (int)gridDim.z;
        if ((nwg & 7) == 0) {
            const int lin = bx + gx * (by + gy * bz);
            const int swz = (lin & 7) * (nwg >> 3) + (lin >> 3);
            bx = swz % gx;
            const int t = swz / gx;
            by = t % gy;
            bz = t / gy;
        }
    }
    const int j0 = bx * 128;
    const int i0 = by * 128;

    const u16* Ab = A + (long)bz * strideA;
    const u16* Bb = B + (long)bz * strideB;

    // staging: per issue, wave w covers 16 rows (lane/4), granule (lane&3)*8
    const int srow = w * 16 + (l >> 2);   // 0..63 (+64 for second issue)
    const int skel = (l & 3) * 8;         // k element offset

    // compute mapping: wave quadrant
    const int i_base = (w >> 1) * 64;
    const int j_base = (w & 1) * 64;
    const int lm = l & 15;
    const int kq = l >> 4;                // 0..3

    floatx4 acc[4][4];
    #pragma unroll
    for (int a = 0; a < 4; ++a)
        #pragma unroll
        for (int b = 0; b < 4; ++b) acc[a][b] = (floatx4)(0.0f);

    auto stage = [&](int buf, int k0) {
        const u16* ga0 = Ab + (long)(i0 + srow) * ldA + k0 + skel;
        const u16* ga1 = Ab + (long)(i0 + 64 + srow) * ldA + k0 + skel;
        const u16* gb0 = Bb + (long)(j0 + srow) * ldB + k0 + skel;
        const u16* gb1 = Bb + (long)(j0 + 64 + srow) * ldB + k0 + skel;
        char* la0 = (char*)&As[buf][0] + w * 1024;
        char* la1 = (char*)&As[buf][0] + 4096 + w * 1024;
        char* lb0 = (char*)&Bs[buf][0] + w * 1024;
        char* lb1 = (char*)&Bs[buf][0] + 4096 + w * 1024;
        __builtin_amdgcn_global_load_lds(
            (const __attribute__((address_space(1))) unsigned int*)(const void*)ga0,
            (__attribute__((address_space(3))) unsigned int*)(void*)la0, 16, 0, 0);
        __builtin_amdgcn_global_load_lds(
            (const __attribute__((address_space(1))) unsigned int*)(const void*)ga1,
            (__attribute__((address_space(3))) unsigned int*)(void*)la1, 16, 0, 0);
        __builtin_amdgcn_global_load_lds(
            (const __attribute__((address_space(1))) unsigned int*)(const void*)gb0,
            (__attribute__((address_space(3))) unsigned int*)(void*)lb0, 16, 0, 0);
        __builtin_amdgcn_global_load_lds(
            (const __attribute__((address_space(1))) unsigned int*)(const void*)gb1,
            (__attribute__((address_space(3))) unsigned int*)(void*)lb1, 16, 0, 0);
    };

    const int nt = K >> 5;            // K-tiles of 32
    stage(0, 0);
    __syncthreads();
    int cur = 0;
    for (int t = 0; t < nt; ++t) {
        if (t + 1 < nt) stage(cur ^ 1, (t + 1) << 5);

        const u16* Ac = &As[cur][0];
        const u16* Bc = &Bs[cur][0];
        half8 af[4], bf[4];
        #pragma unroll
        for (int tt = 0; tt < 4; ++tt) {
            af[tt] = *(const half8*)&Ac[(i_base + tt * 16 + lm) * 32 + kq * 8];
            bf[tt] = *(const half8*)&Bc[(j_base + tt * 16 + lm) * 32 + kq * 8];
        }
        #pragma unroll
        for (int ti = 0; ti < 4; ++ti)
            #pragma unroll
            for (int tj = 0; tj < 4; ++tj)
                acc[ti][tj] = __builtin_amdgcn_mfma_f32_16x16x32_f16(
                    af[ti], bf[tj], acc[ti][tj], 0, 0, 0);
        __syncthreads();
        cur ^= 1;
    }

    OUTT* Cb = C_ + (long)bz * strideC;
    const u16* addb = (MODE == 3) ? addf + (long)bz * strideC : nullptr;
    #pragma unroll
    for (int ti = 0; ti < 4; ++ti) {
        #pragma unroll
        for (int tj = 0; tj < 4; ++tj) {
            const int jj = j0 + j_base + tj * 16 + lm;
            float cinv = 0.f, cbeta = 0.f;
            if (MODE == 1) { cinv = inv_[jj]; cbeta = beta_[jj]; }
            #pragma unroll
            for (int r = 0; r < 4; ++r) {
                const int ii = i0 + i_base + ti * 16 + kq * 4 + r;
                float val = acc[ti][tj][r];
                if (MODE == 1) val = fmaxf(val * cinv + cbeta, 0.0f);
                if (MODE == 2) {
                    float iv = inv_[ii], bt = beta_[ii];
                    val = fmaxf(val * iv + bt, 0.0f);
                }
                if (MODE == 3) val += h2f(addb[(long)ii * ldC + jj]);
                if (sizeof(OUTT) == 4) {
                    ((float*)Cb)[(long)ii * ldC + jj] = val;
                } else {
                    ((u16*)Cb)[(long)ii * ldC + jj] = f2h(val);
                }
            }
        }
    }
}

// ---------------------------------------------------------------------------
// weight fp32 -> fp16 + precompute BN inv/beta
// ---------------------------------------------------------------------------
__global__ __launch_bounds__(256)
void conv_weight(const float* __restrict__ W, const float* __restrict__ g,
                 const float* __restrict__ b, const float* __restrict__ m,
                 const float* __restrict__ v,
                 u16* __restrict__ Wb, float* __restrict__ inv_,
                 float* __restrict__ beta_, int cout, long n)
{
    for (long idx = (long)blockIdx.x * 256 + threadIdx.x; idx < n;
         idx += (long)gridDim.x * 256)
        Wb[idx] = f2h(W[idx]);
    int c = blockIdx.x * 256 + threadIdx.x;
    if (c < cout) {
        float iv = g[c] * rsqrtf(v[c] + EPSV);
        inv_[c] = iv;
        beta_[c] = b[c] - m[c] * iv;
    }
}

// ---------------------------------------------------------------------------
// feature [C][N] fp32 -> featT [N][C] fp16 (32x32 tiled transpose), per batch.
// feature is a READ-ONCE 268 MB stream: non-temporal loads keep it from
// evicting the 67 MB featT output from L3, so the following f-GEMM reads
// featT L3-hot (R13 counters: f ran 261 TF cold vs >520 TF hot elsewhere).
// ---------------------------------------------------------------------------
__global__ __launch_bounds__(256)
void transpose_conv(const float* __restrict__ in, u16* __restrict__ out,
                    int C, int N)
{
    __shared__ float t[32][33];
    const int n0 = blockIdx.x * 32, c0 = blockIdx.y * 32;
    const float* inb = in + (long)blockIdx.z * C * N;
    u16* outb = out + (long)blockIdx.z * C * N;
    const int tx = threadIdx.x & 31, ty = threadIdx.x >> 5;  // 32 x 8
    #pragma unroll
    for (int rr = 0; rr < 32; rr += 8)
        t[ty + rr][tx] =
            __builtin_nontemporal_load(&inb[(long)(c0 + ty + rr) * N + n0 + tx]);
    __syncthreads();
    #pragma unroll
    for (int rr = 0; rr < 32; rr += 8)
        outb[(long)(n0 + ty + rr) * C + c0 + tx] = f2h(t[tx][ty + rr]);
}

// ---------------------------------------------------------------------------
// Row softmax for ONE batch: reads S fp16 [4096][4096] with NON-TEMPORAL
// loads (S is last-use here; nt frees its L3 footprint so the accumulating
// Pc stays resident for the upd GEMM), writes compact P fp16.
// ---------------------------------------------------------------------------
__global__ __launch_bounds__(256)
void softmax_f16(const u16* __restrict__ S, u16* __restrict__ P)
{
    __shared__ float buf[4096];
    __shared__ float red[256];
    const u16* p = S + (long)blockIdx.x * 4096;
    u16* o = P + (long)blockIdx.x * 4096;
    const int tid = threadIdx.x;

    float lmax = -3.4e38f;
    for (int i = tid; i < 4096; i += 256) {
        float x = h2f(__builtin_nontemporal_load(&p[i]));
        buf[i] = x;
        lmax = fmaxf(lmax, x);
    }
    red[tid] = lmax;
    __syncthreads();
    for (int s = 128; s > 0; s >>= 1) {
        if (tid < s) red[tid] = fmaxf(red[tid], red[tid + s]);
        __syncthreads();
    }
    const float mx = red[0];
    __syncthreads();

    float lsum = 0.0f;
    for (int i = tid; i < 4096; i += 256) {
        float e = __expf(buf[i] - mx);
        buf[i] = e;
        lsum += e;
    }
    red[tid] = lsum;
    __syncthreads();
    for (int s = 128; s > 0; s >>= 1) {
        if (tid < s) red[tid] += red[tid + s];
        __syncthreads();
    }
    const float invs = 1.0f / red[0];
    __syncthreads();

    for (int i = tid; i < 4096; i += 256) o[i] = f2h(buf[i] * invs);
}

// ---------------------------------------------------------------------------
extern "C" void kernel_launch(void* const* d_in, const int* in_sizes, int n_in,
                              void* d_out, int out_size, void* d_ws, size_t ws_size,
                              hipStream_t stream)
{
    (void)in_sizes; (void)n_in; (void)out_size; (void)ws_size;
    constexpr int B = 4, C = 2048, R = 512, N = 4096;
    constexpr long NR = (long)N * R;     // 2,097,152
    constexpr long NC = (long)N * C;     // 8,388,608
    constexpr long NN = (long)N * N;     // 16,777,216
    constexpr long NQK = (long)N * 1024;

    const float* feature = (const float*)d_in[0];
    const float* W_[5]  = {(const float*)d_in[1],  (const float*)d_in[6],
                           (const float*)d_in[11], (const float*)d_in[16],
                           (const float*)d_in[21]};
    const float* G_[5]  = {(const float*)d_in[2],  (const float*)d_in[7],
                           (const float*)d_in[12], (const float*)d_in[17],
                           (const float*)d_in[22]};
    const float* Bb_[5] = {(const float*)d_in[3],  (const float*)d_in[8],
                           (const float*)d_in[13], (const float*)d_in[18],
                           (const float*)d_in[23]};
    const float* M_[5]  = {(const float*)d_in[4],  (const float*)d_in[9],
                           (const float*)d_in[14], (const float*)d_in[19],
                           (const float*)d_in[24]};
    const float* V_[5]  = {(const float*)d_in[5],  (const float*)d_in[10],
                           (const float*)d_in[15], (const float*)d_in[20],
                           (const float*)d_in[25]};

    // ---- workspace layout (bytes), ws = 512 MiB ----
    char* base = (char*)d_ws;
    size_t off = 0;
    // region0 (67 MB): featT fp16 [B][N][C] during transpose/f.
    // S fp16 [N][N] (33.5 MB, SINGLE buffer reused across batches -- S[b] is
    // dead after softmax[b]; reuse cuts attention-phase L3 churn 134->33.5 MB
    // so Pc stays L3-resident for upd) aliases featT's head -- featT is dead
    // before the first logits write.
    u16* featT = (u16*)base;
    u16* S     = (u16*)base;
    off += (size_t)B * NC * 2;                         // 67,108,864
    u16* fT  = (u16*)(base + off);                     off += (size_t)B * NR * 2;
    u16* qkT = (u16*)(base + off);                     off += (size_t)B * NQK * 2;
    u16* vC  = (u16*)(base + off);                     off += (size_t)B * NR * 2;
    u16* gT  = (u16*)(base + off);                     off += (size_t)B * NR * 2;
    u16* Pc  = (u16*)(base + off);                     off += (size_t)B * NN * 2;
    // weights (fp16)
    u16* Wb_r  = (u16*)(base + off);  off += (size_t)R * C * 2;       // 2 MB
    u16* WbQK  = (u16*)(base + off);  off += (size_t)1024 * R * 2;    // 1 MB
    u16* Wb_v  = (u16*)(base + off);  off += (size_t)R * R * 2;       // 0.5 MB
    u16* Wb_u  = (u16*)(base + off);  off += (size_t)C * R * 2;       // 2 MB
    off = (off + 255) & ~(size_t)255;
    // BN params
    float* inv_r  = (float*)(base + off);  off += 8192;
    float* beta_r = (float*)(base + off);  off += 8192;
    float* invQK  = (float*)(base + off);  off += 8192;   // [1024]
    float* betaQK = (float*)(base + off);  off += 8192;   // [1024]
    float* inv_v  = (float*)(base + off);  off += 8192;
    float* beta_v = (float*)(base + off);  off += 8192;
    float* inv_u  = (float*)(base + off);  off += 8192;   // [2048]
    float* beta_u = (float*)(base + off);  off += 8192;

    float* out = (float*)d_out;
    const dim3 blk(256);

    // ---- weight conversion + BN param precompute ----
    conv_weight<<<512, blk, 0, stream>>>(W_[0], G_[0], Bb_[0], M_[0], V_[0],
                                         Wb_r, inv_r, beta_r, R, (long)R * C);
    conv_weight<<<512, blk, 0, stream>>>(W_[1], G_[1], Bb_[1], M_[1], V_[1],
                                         WbQK, invQK, betaQK, R, (long)R * R);
    conv_weight<<<512, blk, 0, stream>>>(W_[2], G_[2], Bb_[2], M_[2], V_[2],
                                         WbQK + (size_t)R * R, invQK + R, betaQK + R,
                                         R, (long)R * R);
    conv_weight<<<512, blk, 0, stream>>>(W_[3], G_[3], Bb_[3], M_[3], V_[3],
                                         Wb_v, inv_v, beta_v, R, (long)R * R);
    conv_weight<<<512, blk, 0, stream>>>(W_[4], G_[4], Bb_[4], M_[4], V_[4],
                                         Wb_u, inv_u, beta_u, C, (long)C * R);

    // ---- feature transpose+convert (nt-loads on the fp32 stream):
    // [B][C][N] f32 -> [B][N][C] fp16; featT (67 MB) stays L3-resident ----
    transpose_conv<<<dim3(N / 32, C / 32, B), blk, 0, stream>>>(feature, featT, C, N);

    // ---- f = CBR(feature, r): grid 512, featT L3-hot ----
    gemm_nt<1, u16><<<dim3(R / 128, N / 128, B), blk, 0, stream>>>(
        featT, Wb_r, fT, inv_r, beta_r, nullptr,
        C, C, C, R, NC, 0, NR);

    // ---- q,k merged: qkT [B][N][1024], grid 1024 ----
    gemm_nt<1, u16><<<dim3(1024 / 128, N / 128, B), blk, 0, stream>>>(
        fT, WbQK, qkT, invQK, betaQK, nullptr,
        R, R, R, 1024, NR, 0, NQK);

    // ---- v = CBR(f), channel-major: vC [B][R][N], grid 512 ----
    gemm_nt<2, u16><<<dim3(N / 128, R / 128, B), blk, 0, stream>>>(
        Wb_v, fT, vC, inv_v, beta_v, nullptr,
        R, R, R, N, 0, NR, NR);

    // ---- logits (fp16, SINGLE reused S buffer) + softmax PER BATCH:
    // S = 33.5 MB stays L3-hot for the softmax; softmax nt-reads it so
    // the growing Pc (134 MB) is what L3 keeps for upd. ----
    for (int b = 0; b < B; ++b) {
        gemm_nt<0, u16><<<dim3(N / 128, N / 128, 1), blk, 0, stream>>>(
            qkT + (long)b * NQK, qkT + (long)b * NQK + 512, S,
            nullptr, nullptr, nullptr,
            R, 1024, 1024, N, 0, 0, 0);
        softmax_f16<<<dim3(N), blk, 0, stream>>>(S, Pc + (long)b * NN);
    }

    // ---- upd: gT[b][n][c] = fT + sum_m P[n][m]*vC[c][m], grid 512,
    // Pc L3-resident ----
    gemm_nt<3, u16><<<dim3(R / 128, N / 128, B), blk, 0, stream>>>(
        Pc, vC, gT, nullptr, nullptr, fT,
        N, N, N, R, NN, NR, NR);

    // ---- out = CBR(f + upd, u): grid 2048 ----
    gemm_nt<2, float><<<dim3(N / 128, C / 128, B), blk, 0, stream>>>(
        Wb_u, gT, out, inv_u, beta_u, nullptr,
        R, R, R, N, 0, NR, NC);
}